// Round 1
// baseline (85.337 us; speedup 1.0000x reference)
//
#include <hip/hip_runtime.h>
#include <math.h>

#define NBINS 15
#define THREADS 256
#define SLICE 31   // 15 bins * 2 words + 1 pad (odd stride -> conflict-free banks)
#define GRID 1280  // 5 blocks/CU * 256 CUs

struct Accum {
  double conf[NBINS];
  unsigned int cnt[NBINS];
  unsigned int acc[NBINS];
};

__device__ __forceinline__ void process_row(float l0, float l1, float l2, int lab,
                                            unsigned int* my) {
  float m = fmaxf(l0, fmaxf(l1, l2));
  float s = __expf(l0 - m) + __expf(l1 - m) + __expf(l2 - m);
  float conf = __fdividef(1.0f, s);  // max prob = exp(m-m)/s = 1/s
  int pred = 0;
  float best = l0;
  if (l1 > best) { pred = 1; best = l1; }
  if (l2 > best) { pred = 2; }
  int correct = (pred == lab) ? 1 : 0;
  // bin i covers (i/15, (i+1)/15]; first upper >= conf  ==  ceil(conf*15)-1
  int bin = (int)ceilf(conf * 15.0f) - 1;
  bin = bin < 0 ? 0 : (bin > NBINS - 1 ? NBINS - 1 : bin);
  unsigned int* p = my + 2 * bin;
  p[0] = __float_as_uint(__uint_as_float(p[0]) + conf);
  p[1] += 0x10000u + (unsigned int)correct;  // cnt in high 16, acc in low 16
}

__global__ __launch_bounds__(THREADS, 5) void ece_main(
    const float4* __restrict__ logits4, const int4* __restrict__ labels4,
    Accum* __restrict__ ws, int n) {
  __shared__ unsigned int s_data[THREADS * SLICE];
  const int tid = threadIdx.x;
  unsigned int* my = s_data + tid * SLICE;
#pragma unroll
  for (int i = 0; i < 2 * NBINS; ++i) my[i] = 0;

  const int nquads = n >> 2;
  const int total = gridDim.x * blockDim.x;
  for (int q = blockIdx.x * blockDim.x + tid; q < nquads; q += total) {
    float4 a = logits4[3 * q + 0];
    float4 b = logits4[3 * q + 1];
    float4 c = logits4[3 * q + 2];
    int4 lb = labels4[q];
    process_row(a.x, a.y, a.z, lb.x, my);
    process_row(a.w, b.x, b.y, lb.y, my);
    process_row(b.z, b.w, c.x, lb.z, my);
    process_row(c.y, c.z, c.w, lb.w, my);
  }
  // tail rows if n % 4 != 0 (not hit for N=2^24, kept for generality)
  if (blockIdx.x == 0 && tid == 0) {
    const float* lf = (const float*)logits4;
    const int* li = (const int*)labels4;
    for (int r = nquads * 4; r < n; ++r)
      process_row(lf[3 * r], lf[3 * r + 1], lf[3 * r + 2], li[r], my);
  }

  __syncthreads();
  // tree-reduce the 256 per-thread slices
  for (int offset = THREADS / 2; offset > 0; offset >>= 1) {
    if (tid < offset) {
      unsigned int* a = s_data + tid * SLICE;
      unsigned int* b = s_data + (tid + offset) * SLICE;
#pragma unroll
      for (int bn = 0; bn < NBINS; ++bn) {
        a[2 * bn] = __float_as_uint(__uint_as_float(a[2 * bn]) +
                                    __uint_as_float(b[2 * bn]));
        a[2 * bn + 1] += b[2 * bn + 1];
      }
    }
    __syncthreads();
  }
  if (tid < NBINS) {
    float cs = __uint_as_float(s_data[2 * tid]);
    unsigned int pk = s_data[2 * tid + 1];
    atomicAdd(&ws->conf[tid], (double)cs);
    atomicAdd(&ws->cnt[tid], pk >> 16);
    atomicAdd(&ws->acc[tid], pk & 0xFFFFu);
  }
}

__global__ void ece_final(const Accum* __restrict__ ws, float* __restrict__ out, int n) {
  if (threadIdx.x == 0 && blockIdx.x == 0) {
    double ece = 0.0;
    double dn = (double)n;
    for (int b = 0; b < NBINS; ++b) {
      double cnt = (double)ws->cnt[b];
      if (cnt > 0.0) {
        double gap = fabs(ws->conf[b] / cnt - (double)ws->acc[b] / cnt);
        ece += gap * (cnt / dn);
      }
    }
    out[0] = (float)ece;
  }
}

extern "C" void kernel_launch(void* const* d_in, const int* in_sizes, int n_in,
                              void* d_out, int out_size, void* d_ws, size_t ws_size,
                              hipStream_t stream) {
  const float4* logits4 = (const float4*)d_in[0];
  const int4* labels4 = (const int4*)d_in[1];
  const int n = in_sizes[1];  // rows == number of labels
  Accum* ws = (Accum*)d_ws;
  hipMemsetAsync(d_ws, 0, sizeof(Accum), stream);
  ece_main<<<GRID, THREADS, 0, stream>>>(logits4, labels4, ws, n);
  ece_final<<<1, 64, 0, stream>>>(ws, (float*)d_out, n);
}

// Round 2
// 68.139 us; speedup vs baseline: 1.2524x; 1.2524x over previous
//
#include <hip/hip_runtime.h>
#include <math.h>

#define NBINS 15
#define THREADS 256
#define GRID 2048  // 8 blocks/CU * 256 CUs; 4.19M quads / 524288 threads = 8 iters

struct Accum {
  double d[NBINS];  // sum over bin of (conf - correct); ECE = sum |d[b]| / n
};

// bins 4..14 only reachable for C=3 (conf >= 1/3); accumulators a[0..10] map b-4
__device__ __forceinline__ void process_row(float l0, float l1, float l2, int lab,
                                            float* a) {
  float m = fmaxf(l0, fmaxf(l1, l2));
  float s = __expf(l0 - m) + __expf(l1 - m) + __expf(l2 - m);
  float conf = __fdividef(1.0f, s);  // max prob = 1/s
  int pred = 0;
  float best = l0;
  if (l1 > best) { pred = 1; best = l1; }
  if (l2 > best) { pred = 2; }
  float val = conf - ((pred == lab) ? 1.0f : 0.0f);
  // bin i covers (i/15,(i+1)/15]; searchsorted(uppers, conf, 'left') == ceil(conf*15)-1
  int bin = (int)ceilf(conf * 15.0f) - 1;
  bin = bin < 4 ? 4 : (bin > NBINS - 1 ? NBINS - 1 : bin);
#pragma unroll
  for (int b = 4; b <= 14; ++b) a[b - 4] += (bin == b) ? val : 0.0f;
}

__global__ __launch_bounds__(THREADS, 6) void ece_main(
    const float4* __restrict__ logits4, const int4* __restrict__ labels4,
    Accum* __restrict__ ws, int n) {
  float a[11];
#pragma unroll
  for (int i = 0; i < 11; ++i) a[i] = 0.0f;

  const int nquads = n >> 2;
  const int total = gridDim.x * blockDim.x;
  for (int q = blockIdx.x * blockDim.x + threadIdx.x; q < nquads; q += total) {
    float4 x = logits4[3 * q + 0];
    float4 y = logits4[3 * q + 1];
    float4 z = logits4[3 * q + 2];
    int4 lb = labels4[q];
    process_row(x.x, x.y, x.z, lb.x, a);
    process_row(x.w, y.x, y.y, lb.y, a);
    process_row(y.z, y.w, z.x, lb.z, a);
    process_row(z.y, z.z, z.w, lb.w, a);
  }
  // tail rows if n % 4 != 0 (not hit for N=2^24)
  if (blockIdx.x == 0 && threadIdx.x == 0) {
    const float* lf = (const float*)logits4;
    const int* li = (const int*)labels4;
    for (int r = (n >> 2) << 2; r < n; ++r)
      process_row(lf[3 * r], lf[3 * r + 1], lf[3 * r + 2], li[r], a);
  }

  // wave-level butterfly reduce (64 lanes)
#pragma unroll
  for (int i = 0; i < 11; ++i) {
    float v = a[i];
    for (int off = 32; off > 0; off >>= 1) v += __shfl_down(v, off, 64);
    a[i] = v;
  }
  __shared__ float s_part[THREADS / 64][11];
  const int wave = threadIdx.x >> 6;
  const int lane = threadIdx.x & 63;
  if (lane == 0) {
#pragma unroll
    for (int i = 0; i < 11; ++i) s_part[wave][i] = a[i];
  }
  __syncthreads();
  if (threadIdx.x < 11) {
    float v = 0.0f;
#pragma unroll
    for (int w = 0; w < THREADS / 64; ++w) v += s_part[w][threadIdx.x];
    atomicAdd(&ws->d[threadIdx.x + 4], (double)v);
  }
}

__global__ void ece_final(const Accum* __restrict__ ws, float* __restrict__ out, int n) {
  if (threadIdx.x == 0 && blockIdx.x == 0) {
    double ece = 0.0;
    for (int b = 0; b < NBINS; ++b) ece += fabs(ws->d[b]);
    out[0] = (float)(ece / (double)n);
  }
}

extern "C" void kernel_launch(void* const* d_in, const int* in_sizes, int n_in,
                              void* d_out, int out_size, void* d_ws, size_t ws_size,
                              hipStream_t stream) {
  const float4* logits4 = (const float4*)d_in[0];
  const int4* labels4 = (const int4*)d_in[1];
  const int n = in_sizes[1];  // rows == number of labels
  Accum* ws = (Accum*)d_ws;
  hipMemsetAsync(d_ws, 0, sizeof(Accum), stream);
  ece_main<<<GRID, THREADS, 0, stream>>>(logits4, labels4, ws, n);
  ece_final<<<1, 64, 0, stream>>>(ws, (float*)d_out, n);
}